// Round 9
// baseline (387.655 us; speedup 1.0000x reference)
//
#include <hip/hip_runtime.h>
#include <hip/hip_bf16.h>
#include <math.h>

typedef __attribute__((ext_vector_type(8))) short short8;
typedef __attribute__((ext_vector_type(4))) float f32x4;

#define MU_  0.1f
#define THR_ 0.01f

static __device__ inline short f2bf(float f) {
    __hip_bfloat16 h = __float2bfloat16(f);
    return *reinterpret_cast<short*>(&h);
}
static __device__ inline float bf2f(unsigned short u) {
    unsigned int x = ((unsigned int)u) << 16;
    return __builtin_bit_cast(float, x);
}

#define ZB_ 5916   // zero blocks: 1,514,496 float4 / 256

// ---------------------------------------------------------------------------
// Merged prep: [0,ZB_) zero Rp+Yp pads; [ZB_,ZB_+32) wnorm (4 co/block);
// [ZB_+32,...) pack_x rows.
//  Wf2[t][ci>>3][co][ci&7] = Wn[co][ci*9+t]        (fwd A, k-major chunks)
//  Wt2[t][co>>3][ci][co&7] = Wn[co][ci*9+(8-t)]    (conv_t A, k-major chunks)
// ---------------------------------------------------------------------------
__global__ __launch_bounds__(256) void prep_kernel(
    const float* __restrict__ x, const float* __restrict__ W,
    float4* __restrict__ zbase, int n4,
    short* __restrict__ Xp, short* __restrict__ Wf2, short* __restrict__ Wt2) {
    __shared__ float lx[64 * 57];
    const int bid = blockIdx.x, tid = threadIdx.x;
    if (bid < ZB_) {
        int i = bid * 256 + tid;
        if (i < n4) zbase[i] = make_float4(0.f, 0.f, 0.f, 0.f);
    } else if (bid < ZB_ + 32) {
        int co = (bid - ZB_) * 4 + (tid >> 6);
        int ci = tid & 63;
        const float* wp = W + (co * 64 + ci) * 9;
        float v[9]; float s = 0.f;
#pragma unroll
        for (int t = 0; t < 9; ++t) { v[t] = wp[t]; s += v[t] * v[t]; }
#pragma unroll
        for (int off = 32; off; off >>= 1) s += __shfl_xor(s, off, 64);
        float inv = 1.0f / sqrtf(s + 1e-12f);
#pragma unroll
        for (int t = 0; t < 9; ++t) {
            Wf2[((t * 8 + (ci >> 3)) * 128 + co) * 8 + (ci & 7)] = f2bf(v[t] * inv);
            Wt2[((t * 16 + (co >> 3)) * 64 + ci) * 8 + (co & 7)] = f2bf(v[8 - t] * inv);
        }
    } else {
        int pb = bid - ZB_ - 32;
        int row = pb % 58, n = pb / 58;
        short* dst = Xp + ((size_t)(n * 58 + row) * 68) * 64;
        if (row >= 1 && row <= 56) {
            int h = row - 1;
            for (int j = tid; j < 64 * 56; j += 256) {
                int ci = j / 56, w = j - ci * 56;
                lx[ci * 57 + w] = x[((size_t)(n * 64 + ci)) * 3136 + h * 56 + w];
            }
            __syncthreads();
            for (int j = tid; j < 68 * 64; j += 256) {
                int s = j >> 6, ci = j & 63;
                float val = (s >= 2 && s < 58) ? lx[ci * 57 + (s - 2)] : 0.f;
                dst[(s << 6) + (ci ^ ((s & 7) << 3))] = f2bf(val);
            }
        } else {
            for (int j = tid; j < 68 * 64; j += 256) dst[j] = 0;
        }
    }
}

// ---------------------------------------------------------------------------
// Forward conv 64->128, 16x16x32 MFMA, A register-resident, 2 output rows
// per block. grid=(28, 2 co-halves, 16 n), block=256 (4 waves = 4 co-tiles;
// each wave: 2 rows x 4 px-tiles). B in LDS, 72-short padded rows.
// mode 0: c=shrink(MU*acc); y=cp=c
// mode 1: c=shrink(y_old+MU*acc); y=c+beta*(c-cp_old); cp=c
// mode 2: out=shrink(y_old+MU*acc) (fp32 NCHW, no state writes)
// ---------------------------------------------------------------------------
__global__ __launch_bounds__(256) void conv_fwd(
    const short* __restrict__ inp,   // [n][58][68][64] bf16 swz (Xp or Rp)
    const short* __restrict__ Wf2,   // [9][8][128][8] bf16 k-major chunks
    short* __restrict__ Yp,          // [n][58][68][128] bf16 swz (y state)
    short* __restrict__ Cp,          // [n][58][68][128] bf16 swz (c_prev)
    float* __restrict__ outp, int mode, float beta) {
    __shared__ __align__(16) short smem[19584];   // 272 rows x 72 shorts
    const int r0 = blockIdx.x * 2 + 1, cb = blockIdx.y, n = blockIdx.z, tid = threadIdx.x;
    {   // stage B: 4 input rows (r0-1 .. r0+2)
        const short8* src = (const short8*)(inp + ((size_t)(n * 58 + (r0 - 1)) * 68) * 64);
        for (int j = tid; j < 2176; j += 256) {
            int srow = j >> 3, w = j & 7;
            *(short8*)(smem + srow * 72 + w * 8) = src[j];
        }
    }
    const int lane = tid & 63, ct = tid >> 6, quad = lane >> 4, l15 = lane & 15;
    const int co = cb * 64 + ct * 16 + l15;
    const size_t prow0 = ((size_t)(n * 58 + r0) * 68) * 128;

    // prefetch old y (2 rows x 448 coalesced short8 items; rides under MFMA)
    short8 yold8[4];
    if (mode != 0) {
#pragma unroll
        for (int k = 0; k < 4; ++k) {
            int item = tid + k * 256;
            if (item < 896) {
                int rr = item >= 448;
                int rem = item - rr * 448;
                int vv = rem >> 3, g = rem & 7;
                int s = vv + 2;
                yold8[k] = *(const short8*)(Yp + prow0 + (size_t)rr * 8704 +
                                            (size_t)s * 128 + 8 * ((g + 8 * cb) ^ (s & 7)));
            }
        }
    }

    short8 Areg[18];                 // k frag f: t=f>>1, half=f&1
#pragma unroll
    for (int f = 0; f < 18; ++f) {
        int t = f >> 1, half = f & 1;
        Areg[f] = *(const short8*)(Wf2 + ((size_t)((t * 8 + half * 4 + quad) * 128 + co)) * 8);
    }
    __syncthreads();

    f32x4 acc[2][4];
#pragma unroll
    for (int rr = 0; rr < 2; ++rr)
#pragma unroll
        for (int pt = 0; pt < 4; ++pt) acc[rr][pt] = (f32x4){0.f, 0.f, 0.f, 0.f};

#pragma unroll
    for (int f = 0; f < 18; ++f) {
        const int t = f >> 1, half = f & 1;
        const int dh = t / 3, dw = t % 3;
        const int u = l15 + dw + 1;
        const int phys = (half * 4 + quad) ^ (u & 7);
        const int cbase = u * 72 + phys * 8;
#pragma unroll
        for (int rr = 0; rr < 2; ++rr) {
            const int base = (rr + dh) * 4896 + cbase;   // 68*72 = 4896/row
#pragma unroll
            for (int pt = 0; pt < 4; ++pt) {
                short8 bv = *(const short8*)(smem + base + pt * 1152);
                acc[rr][pt] = __builtin_amdgcn_mfma_f32_16x16x32_bf16(Areg[f], bv, acc[rr][pt], 0, 0, 0);
            }
        }
    }

    // ---- epilogue: state bounce via LDS (smem dead) ----
    __syncthreads();
    short* tb_y = smem;              // 2 x 4608 shorts
    short* tb_c = smem + 9216;       // 2 x 4608 shorts
    if (mode != 0) {
#pragma unroll
        for (int k = 0; k < 4; ++k) {
            int item = tid + k * 256;
            if (item < 896) {
                int rr = item >= 448;
                int rem = item - rr * 448;
                int vv = rem >> 3, g = rem & 7;
                int o = rr * 4608 + vv * 72 + 8 * (g ^ (vv & 3));
                *(short8*)(tb_y + o) = yold8[k];
                if (mode == 1) {
                    int s = vv + 2;
                    size_t off = prow0 + (size_t)rr * 8704 + (size_t)s * 128 +
                                 8 * ((g + 8 * cb) ^ (s & 7));
                    *(short8*)(tb_c + o) = *(const short8*)(Cp + off);
                }
            }
        }
    }
    __syncthreads();
    const int h0 = r0 - 1;
#pragma unroll
    for (int rr = 0; rr < 2; ++rr) {
#pragma unroll
        for (int pt = 0; pt < 4; ++pt) {
            const int px = pt * 16 + l15;
#pragma unroll
            for (int reg = 0; reg < 4; ++reg) {
                const int lch = ct * 16 + quad * 4 + reg;      // 0..63
                const int slot = rr * 4608 + px * 72 + (lch ^ ((px & 3) << 3));
                const float a = acc[rr][pt][reg];
                if (mode == 0) {
                    float c = fmaxf(MU_ * a - THR_, 0.f);
                    short cb16 = f2bf(c);
                    tb_y[slot] = cb16;
                    tb_c[slot] = cb16;
                } else if (mode == 1) {
                    float yold = bf2f((unsigned short)tb_y[slot]);
                    float cold = bf2f((unsigned short)tb_c[slot]);
                    float c = fmaxf(yold + MU_ * a - THR_, 0.f);
                    tb_y[slot] = f2bf(c + beta * (c - cold));
                    tb_c[slot] = f2bf(c);
                } else {
                    if (px < 56) {
                        float yold = bf2f((unsigned short)tb_y[slot]);
                        float c = fmaxf(yold + MU_ * a - THR_, 0.f);
                        outp[((size_t)(n * 128 + cb * 64 + lch)) * 3136 +
                             (h0 + rr) * 56 + px] = c;
                    }
                }
            }
        }
    }
    if (mode != 2) {
        __syncthreads();
        for (int item = tid; item < 896; item += 256) {
            int rr = item >= 448;
            int rem = item - rr * 448;
            int vv = rem >> 3, g = rem & 7;
            int so = rr * 4608 + vv * 72 + 8 * (g ^ (vv & 3));
            short8 yv = *(const short8*)(tb_y + so);
            short8 cv = *(const short8*)(tb_c + so);
            int s = vv + 2;
            size_t off = prow0 + (size_t)rr * 8704 + (size_t)s * 128 +
                         8 * ((g + 8 * cb) ^ (s & 7));
            *(short8*)(Yp + off) = yv;
            *(short8*)(Cp + off) = cv;
        }
    }
}

// ---------------------------------------------------------------------------
// Transpose conv 128->64, 16x16x32 MFMA, A register-resident per co-half
// pass, 2 output rows per block. Fused residual r = x - D^T y (x from Xp).
// grid=(28,16), block=256.
// ---------------------------------------------------------------------------
__global__ __launch_bounds__(256) void conv_t(
    const short* __restrict__ Ypb,   // [n][58][68][128] bf16 swz
    const short* __restrict__ Wt2,   // [9][16][64][8] bf16 k-major chunks
    const short* __restrict__ Xp,    // [n][58][68][64] bf16 swz
    short* __restrict__ Rp) {        // [n][58][68][64] bf16 swz
    __shared__ __align__(16) short smem[19584];   // 272 rows x 72 shorts
    const int r0 = blockIdx.x * 2 + 1, n = blockIdx.y, tid = threadIdx.x;
    const int lane = tid & 63, ct = tid >> 6, quad = lane >> 4, l15 = lane & 15;
    const int ci = ct * 16 + l15;
    const short8* src = (const short8*)(Ypb + ((size_t)(n * 58 + (r0 - 1)) * 68) * 128);
    const size_t prow0 = ((size_t)(n * 58 + r0) * 68) * 64;

    // prefetch x rows (2 x 448 coalesced short8 items)
    short8 xold8[4];
#pragma unroll
    for (int k = 0; k < 4; ++k) {
        int item = tid + k * 256;
        if (item < 896) {
            int rr = item >= 448;
            int rem = item - rr * 448;
            int vv = rem >> 3, g = rem & 7;
            int s = vv + 2;
            xold8[k] = *(const short8*)(Xp + prow0 + (size_t)rr * 4352 +
                                        (size_t)s * 64 + 8 * (g ^ (s & 7)));
        }
    }

    f32x4 acc[2][4];
#pragma unroll
    for (int rr = 0; rr < 2; ++rr)
#pragma unroll
        for (int pt = 0; pt < 4; ++pt) acc[rr][pt] = (f32x4){0.f, 0.f, 0.f, 0.f};

#pragma unroll
    for (int p = 0; p < 2; ++p) {
        if (p) __syncthreads();      // prior pass's B reads complete
        // stage phys chunk-half p of 4 input rows (contig 128 B per 256 B row)
        for (int j = tid; j < 2176; j += 256) {
            int srow = j >> 3, w = j & 7;
            *(short8*)(smem + srow * 72 + w * 8) = src[srow * 16 + p * 8 + w];
        }
        short8 Areg[18];             // k frag f: t=f>>1, sub=p*2+(f&1)
#pragma unroll
        for (int f = 0; f < 18; ++f) {
            int t = f >> 1, sh = f & 1;
            Areg[f] = *(const short8*)(Wt2 +
                ((size_t)((t * 16 + (p * 2 + sh) * 4 + quad) * 64 + ci)) * 8);
        }
        __syncthreads();
#pragma unroll
        for (int f = 0; f < 18; ++f) {
            const int t = f >> 1, sh = f & 1;
            const int dh = t / 3, dw = t % 3;
            const int u = l15 + dw + 1;
            const int phys = (sh * 4 + quad) ^ (u & 7);
            const int cbase = u * 72 + phys * 8;
#pragma unroll
            for (int rr = 0; rr < 2; ++rr) {
                const int base = (rr + dh) * 4896 + cbase;
#pragma unroll
                for (int pt = 0; pt < 4; ++pt) {
                    short8 bv = *(const short8*)(smem + base + pt * 1152);
                    acc[rr][pt] = __builtin_amdgcn_mfma_f32_16x16x32_bf16(Areg[f], bv, acc[rr][pt], 0, 0, 0);
                }
            }
        }
    }

    // ---- epilogue: r = x - acc via LDS bounce ----
    __syncthreads();
    short* tb = smem;                // 2 x 4608 shorts
#pragma unroll
    for (int k = 0; k < 4; ++k) {
        int item = tid + k * 256;
        if (item < 896) {
            int rr = item >= 448;
            int rem = item - rr * 448;
            int vv = rem >> 3, g = rem & 7;
            *(short8*)(tb + rr * 4608 + vv * 72 + 8 * (g ^ (vv & 3))) = xold8[k];
        }
    }
    __syncthreads();
#pragma unroll
    for (int rr = 0; rr < 2; ++rr) {
#pragma unroll
        for (int pt = 0; pt < 4; ++pt) {
            const int px = pt * 16 + l15;
#pragma unroll
            for (int reg = 0; reg < 4; ++reg) {
                const int cir = ct * 16 + quad * 4 + reg;
                const int slot = rr * 4608 + px * 72 + (cir ^ ((px & 3) << 3));
                float xo = bf2f((unsigned short)tb[slot]);
                tb[slot] = f2bf(xo - acc[rr][pt][reg]);
            }
        }
    }
    __syncthreads();
    for (int item = tid; item < 896; item += 256) {
        int rr = item >= 448;
        int rem = item - rr * 448;
        int vv = rem >> 3, g = rem & 7;
        short8 val = *(const short8*)(tb + rr * 4608 + vv * 72 + 8 * (g ^ (vv & 3)));
        int s = vv + 2;
        *(short8*)(Rp + prow0 + (size_t)rr * 4352 + (size_t)s * 64 + 8 * (g ^ (s & 7))) = val;
    }
}

// ---------------------------------------------------------------------------
extern "C" void kernel_launch(void* const* d_in, const int* in_sizes, int n_in,
                              void* d_out, int out_size, void* d_ws, size_t ws_size,
                              hipStream_t stream) {
    const float* x = (const float*)d_in[0];   // [16,64,56,56] fp32
    const float* W = (const float*)d_in[1];   // [128,64,3,3]  fp32
    float* out = (float*)d_out;               // [16,128,56,56] fp32

    // ws layout (all bf16): Xp | Rp | Yp | Cp | Wf2 | Wt2  (~49 MB)
    const size_t XPN = (size_t)16 * 58 * 68 * 64;   // 4,038,656
    const size_t YPN = 2 * XPN;                      // 8,077,312
    short* Xp = (short*)d_ws;
    short* Rp = Xp + XPN;
    short* Yp = Rp + XPN;
    short* Cp = Yp + YPN;
    short* Wf2 = Cp + YPN;                // 73728 shorts
    short* Wt2 = Wf2 + 73728;             // 73728 shorts

    const int n4 = (int)((XPN + YPN) * 2 / 16);     // 1,514,496 (ZB_=5916)
    const int prep_blocks = ZB_ + 32 + 58 * 16;     // 6876
    hipLaunchKernelGGL(prep_kernel, dim3(prep_blocks), dim3(256), 0, stream,
                       x, W, (float4*)Rp, n4, Xp, Wf2, Wt2);

    dim3 gf(28, 2, 16), gt(28, 16), b(256, 1, 1);
    // it0: c = shrink(MU * conv(x)); y = cp = c
    hipLaunchKernelGGL(conv_fwd, gf, b, 0, stream, Xp, Wf2, Yp, Cp,
                       (float*)nullptr, 0, 0.f);
    double t = 1.0;
    for (int it = 1; it <= 5; ++it) {
        hipLaunchKernelGGL(conv_t, gt, b, 0, stream, Yp, Wt2, Xp, Rp);
        double tn = (1.0 + sqrt(1.0 + 4.0 * t * t)) / 2.0;
        float beta = (float)((t - 1.0) / tn);
        hipLaunchKernelGGL(conv_fwd, gf, b, 0, stream, Rp, Wf2, Yp, Cp,
                           (it == 5) ? out : (float*)nullptr, (it == 5) ? 2 : 1,
                           beta);
        t = tn;
    }
}

// Round 10
// 360.533 us; speedup vs baseline: 1.0752x; 1.0752x over previous
//
#include <hip/hip_runtime.h>
#include <hip/hip_bf16.h>
#include <math.h>

typedef __attribute__((ext_vector_type(8))) short short8;
typedef __attribute__((ext_vector_type(4))) float f32x4;

#define MU_  0.1f
#define THR_ 0.01f

static __device__ inline short f2bf(float f) {
    __hip_bfloat16 h = __float2bfloat16(f);
    return *reinterpret_cast<short*>(&h);
}
static __device__ inline float bf2f(unsigned short u) {
    unsigned int x = ((unsigned int)u) << 16;
    return __builtin_bit_cast(float, x);
}

#define ZB_ 5916   // zero blocks: 1,514,496 float4 / 256

// ---------------------------------------------------------------------------
// Merged prep: [0,ZB_) zero Rp+Yp pads; [ZB_,ZB_+32) wnorm (4 co/block);
// [ZB_+32,...) pack_x rows.
//  Wf2[t][ci>>3][co][ci&7] = Wn[co][ci*9+t]        (fwd A, k-major chunks)
//  Wt2[t][co>>3][ci][co&7] = Wn[co][ci*9+(8-t)]    (conv_t A, k-major chunks)
// ---------------------------------------------------------------------------
__global__ __launch_bounds__(256) void prep_kernel(
    const float* __restrict__ x, const float* __restrict__ W,
    float4* __restrict__ zbase, int n4,
    short* __restrict__ Xp, short* __restrict__ Wf2, short* __restrict__ Wt2) {
    __shared__ float lx[64 * 57];
    const int bid = blockIdx.x, tid = threadIdx.x;
    if (bid < ZB_) {
        int i = bid * 256 + tid;
        if (i < n4) zbase[i] = make_float4(0.f, 0.f, 0.f, 0.f);
    } else if (bid < ZB_ + 32) {
        int co = (bid - ZB_) * 4 + (tid >> 6);
        int ci = tid & 63;
        const float* wp = W + (co * 64 + ci) * 9;
        float v[9]; float s = 0.f;
#pragma unroll
        for (int t = 0; t < 9; ++t) { v[t] = wp[t]; s += v[t] * v[t]; }
#pragma unroll
        for (int off = 32; off; off >>= 1) s += __shfl_xor(s, off, 64);
        float inv = 1.0f / sqrtf(s + 1e-12f);
#pragma unroll
        for (int t = 0; t < 9; ++t) {
            Wf2[((t * 8 + (ci >> 3)) * 128 + co) * 8 + (ci & 7)] = f2bf(v[t] * inv);
            Wt2[((t * 16 + (co >> 3)) * 64 + ci) * 8 + (co & 7)] = f2bf(v[8 - t] * inv);
        }
    } else {
        int pb = bid - ZB_ - 32;
        int row = pb % 58, n = pb / 58;
        short* dst = Xp + ((size_t)(n * 58 + row) * 68) * 64;
        if (row >= 1 && row <= 56) {
            int h = row - 1;
            for (int j = tid; j < 64 * 56; j += 256) {
                int ci = j / 56, w = j - ci * 56;
                lx[ci * 57 + w] = x[((size_t)(n * 64 + ci)) * 3136 + h * 56 + w];
            }
            __syncthreads();
            for (int j = tid; j < 68 * 64; j += 256) {
                int s = j >> 6, ci = j & 63;
                float val = (s >= 2 && s < 58) ? lx[ci * 57 + (s - 2)] : 0.f;
                dst[(s << 6) + (ci ^ ((s & 7) << 3))] = f2bf(val);
            }
        } else {
            for (int j = tid; j < 68 * 64; j += 256) dst[j] = 0;
        }
    }
}

// ---------------------------------------------------------------------------
// Forward conv 64->128, 16x16x32 MFMA, A register-resident in two 9-frag
// passes (36 VGPR), 1 output row/block. grid = 1792 flat:
//   cb = bid/896 (co-half), q = bid%896, sid = (q%8)*112 + q/8  (XCD-local),
//   row r = sid%56 + 1, n = sid/56.  Same sid->XCD map as conv_t.
// mode 0: c=shrink(MU*acc); y=cp=c
// mode 1: c=shrink(y_old+MU*acc); y=c+beta*(c-cp_old); cp=c
// mode 2: out=shrink(y_old+MU*acc) (fp32 NCHW, no state writes)
// ---------------------------------------------------------------------------
__global__ __launch_bounds__(256, 4) void conv_fwd(
    const short* __restrict__ inp,   // [n][58][68][64] bf16 swz (Xp or Rp)
    const short* __restrict__ Wf2,   // [9][8][128][8] bf16 k-major chunks
    short* __restrict__ Yp,          // [n][58][68][128] bf16 swz (y state)
    short* __restrict__ Cp,          // [n][58][68][128] bf16 swz (c_prev)
    float* __restrict__ outp, int mode, float beta) {
    __shared__ __align__(16) short smem[14688];   // 204 rows x 72 shorts
    const int bid = blockIdx.x, tid = threadIdx.x;
    const int cb = bid >= 896;
    const int q = bid - cb * 896;
    const int sid = (q & 7) * 112 + (q >> 3);
    const int n = sid / 56, r = sid - n * 56 + 1;
    {   // stage B: 3 input rows, 64-short global rows -> 72-short LDS rows
        const short8* src = (const short8*)(inp + ((size_t)(n * 58 + (r - 1)) * 68) * 64);
        for (int j = tid; j < 1632; j += 256) {
            int srow = j >> 3, w = j & 7;
            *(short8*)(smem + srow * 72 + w * 8) = src[j];
        }
    }
    const int lane = tid & 63, ct = tid >> 6, quad = lane >> 4, l15 = lane & 15;
    const int co = cb * 64 + ct * 16 + l15;
    const size_t prow = ((size_t)(n * 58 + r) * 68) * 128;

    // pre-loop coalesced prefetch of old y / c_prev (448 short8 items)
    short8 yold8[2], cold8[2];
    int pvv[2], pg[2]; bool pok[2];
#pragma unroll
    for (int k = 0; k < 2; ++k) {
        int item = tid + k * 256;
        pok[k] = item < 448;
        pvv[k] = item >> 3; pg[k] = item & 7;
        if (mode != 0 && pok[k]) {
            int s = pvv[k] + 2;
            size_t off = prow + (size_t)s * 128 + 8 * ((pg[k] + 8 * cb) ^ (s & 7));
            yold8[k] = *(const short8*)(Yp + off);
            if (mode == 1) cold8[k] = *(const short8*)(Cp + off);
        }
    }
    __syncthreads();

    f32x4 acc[4];
#pragma unroll
    for (int pt = 0; pt < 4; ++pt) acc[pt] = (f32x4){0.f, 0.f, 0.f, 0.f};

#pragma unroll
    for (int hp = 0; hp < 2; ++hp) {      // two 9-frag A passes (36 VGPR)
        short8 Areg[9];
#pragma unroll
        for (int i = 0; i < 9; ++i) {
            int f = hp * 9 + i, t = f >> 1, half = f & 1;
            Areg[i] = *(const short8*)(Wf2 +
                ((size_t)((t * 8 + half * 4 + quad) * 128 + co)) * 8);
        }
#pragma unroll
        for (int i = 0; i < 9; ++i) {
            const int f = hp * 9 + i, t = f >> 1, half = f & 1;
            const int dh = t / 3, dw = t % 3;
            const int u = l15 + dw + 1;
            const int phys = (half * 4 + quad) ^ (u & 7);
            const int base = (dh * 68 + u) * 72 + phys * 8;
#pragma unroll
            for (int pt = 0; pt < 4; ++pt) {
                short8 bv = *(const short8*)(smem + base + pt * 1152);
                acc[pt] = __builtin_amdgcn_mfma_f32_16x16x32_bf16(Areg[i], bv, acc[pt], 0, 0, 0);
            }
        }
    }

    // ---- epilogue: state bounce via LDS (smem dead) ----
    __syncthreads();
    short* tb_y = smem;              // [64 px][72 ch-half]
    short* tb_c = smem + 4608;
    if (mode != 0) {
#pragma unroll
        for (int k = 0; k < 2; ++k) if (pok[k]) {
            int o = pvv[k] * 72 + 8 * (pg[k] ^ (pvv[k] & 3));
            *(short8*)(tb_y + o) = yold8[k];
            if (mode == 1) *(short8*)(tb_c + o) = cold8[k];
        }
    }
    __syncthreads();
    const int h = r - 1;
#pragma unroll
    for (int pt = 0; pt < 4; ++pt) {
        const int px = pt * 16 + l15;
#pragma unroll
        for (int reg = 0; reg < 4; ++reg) {
            const int lch = ct * 16 + quad * 4 + reg;      // 0..63 (half-local)
            const int slot = px * 72 + (lch ^ ((px & 3) << 3));
            const float a = acc[pt][reg];
            if (mode == 0) {
                float c = fmaxf(MU_ * a - THR_, 0.f);
                short cb16 = f2bf(c);
                tb_y[slot] = cb16;
                tb_c[slot] = cb16;
            } else if (mode == 1) {
                float yold = bf2f((unsigned short)tb_y[slot]);
                float cold = bf2f((unsigned short)tb_c[slot]);
                float c = fmaxf(yold + MU_ * a - THR_, 0.f);
                tb_y[slot] = f2bf(c + beta * (c - cold));
                tb_c[slot] = f2bf(c);
            } else {
                if (px < 56) {
                    float yold = bf2f((unsigned short)tb_y[slot]);
                    float c = fmaxf(yold + MU_ * a - THR_, 0.f);
                    outp[((size_t)(n * 128 + cb * 64 + lch)) * 3136 + h * 56 + px] = c;
                }
            }
        }
    }
    if (mode != 2) {
        __syncthreads();
        for (int item = tid; item < 448; item += 256) {
            int vv = item >> 3, g = item & 7;
            int so = vv * 72 + 8 * (g ^ (vv & 3));
            short8 yv = *(const short8*)(tb_y + so);
            short8 cv = *(const short8*)(tb_c + so);
            int s = vv + 2;
            size_t off = prow + (size_t)s * 128 + 8 * ((g + 8 * cb) ^ (s & 7));
            *(short8*)(Yp + off) = yv;
            *(short8*)(Cp + off) = cv;
        }
    }
}

// ---------------------------------------------------------------------------
// Transpose conv 128->64, 16x16x32 MFMA, A in 9-frag register passes,
// 2 LDS passes over K (phys chunk halves), 1 output row/block.
// grid = 896 flat: sid = (bid%8)*112 + bid/8 (same XCD map as conv_fwd).
// Fused residual r = x - D^T y (x from Xp).
// ---------------------------------------------------------------------------
__global__ __launch_bounds__(256, 4) void conv_t(
    const short* __restrict__ Ypb,   // [n][58][68][128] bf16 swz
    const short* __restrict__ Wt2,   // [9][16][64][8] bf16 k-major chunks
    const short* __restrict__ Xp,    // [n][58][68][64] bf16 swz
    short* __restrict__ Rp) {        // [n][58][68][64] bf16 swz
    __shared__ __align__(16) short smem[14688];   // 204 rows x 72 shorts
    const int bid = blockIdx.x, tid = threadIdx.x;
    const int sid = (bid & 7) * 112 + (bid >> 3);
    const int n = sid / 56, r = sid - n * 56 + 1;
    const int lane = tid & 63, ct = tid >> 6, quad = lane >> 4, l15 = lane & 15;
    const int ci = ct * 16 + l15;
    const short8* src = (const short8*)(Ypb + ((size_t)(n * 58 + (r - 1)) * 68) * 128);
    const size_t prow = ((size_t)(n * 58 + r) * 68) * 64;

    // pre-loop coalesced prefetch of x row (448 short8 items)
    short8 xold8[2];
    int pvv[2], pg[2]; bool pok[2];
#pragma unroll
    for (int k = 0; k < 2; ++k) {
        int item = tid + k * 256;
        pok[k] = item < 448;
        pvv[k] = item >> 3; pg[k] = item & 7;
        if (pok[k]) {
            int s = pvv[k] + 2;
            xold8[k] = *(const short8*)(Xp + prow + (size_t)s * 64 + 8 * (pg[k] ^ (s & 7)));
        }
    }

    f32x4 acc[4];
#pragma unroll
    for (int pt = 0; pt < 4; ++pt) acc[pt] = (f32x4){0.f, 0.f, 0.f, 0.f};

#pragma unroll
    for (int p = 0; p < 2; ++p) {
        if (p) __syncthreads();      // prior pass's B reads complete
        // stage phys chunk-half p of 3 input rows (contig 128 B per 256 B row)
        for (int j = tid; j < 1632; j += 256) {
            int srow = j >> 3, w = j & 7;
            *(short8*)(smem + srow * 72 + w * 8) = src[srow * 16 + p * 8 + w];
        }
        __syncthreads();
#pragma unroll
        for (int sub = 0; sub < 2; ++sub) {   // two 9-frag A passes
            short8 Areg[9];
#pragma unroll
            for (int i = 0; i < 9; ++i) {
                int f = sub * 9 + i, t = f >> 1, sh = f & 1;
                Areg[i] = *(const short8*)(Wt2 +
                    ((size_t)((t * 16 + (p * 2 + sh) * 4 + quad) * 64 + ci)) * 8);
            }
#pragma unroll
            for (int i = 0; i < 9; ++i) {
                const int f = sub * 9 + i, t = f >> 1, sh = f & 1;
                const int dh = t / 3, dw = t % 3;
                const int u = l15 + dw + 1;
                const int phys = (sh * 4 + quad) ^ (u & 7);
                const int base = (dh * 68 + u) * 72 + phys * 8;
#pragma unroll
                for (int pt = 0; pt < 4; ++pt) {
                    short8 bv = *(const short8*)(smem + base + pt * 1152);
                    acc[pt] = __builtin_amdgcn_mfma_f32_16x16x32_bf16(Areg[i], bv, acc[pt], 0, 0, 0);
                }
            }
        }
    }

    // ---- epilogue: r = x - acc via LDS bounce ----
    __syncthreads();
    short* tb = smem;                // [64 px][72 ch]
#pragma unroll
    for (int k = 0; k < 2; ++k) if (pok[k]) {
        *(short8*)(tb + pvv[k] * 72 + 8 * (pg[k] ^ (pvv[k] & 3))) = xold8[k];
    }
    __syncthreads();
#pragma unroll
    for (int pt = 0; pt < 4; ++pt) {
        const int px = pt * 16 + l15;
#pragma unroll
        for (int reg = 0; reg < 4; ++reg) {
            const int cir = ct * 16 + quad * 4 + reg;
            const int slot = px * 72 + (cir ^ ((px & 3) << 3));
            float xo = bf2f((unsigned short)tb[slot]);
            tb[slot] = f2bf(xo - acc[pt][reg]);
        }
    }
    __syncthreads();
    for (int item = tid; item < 448; item += 256) {
        int vv = item >> 3, g = item & 7;
        short8 val = *(const short8*)(tb + vv * 72 + 8 * (g ^ (vv & 3)));
        int s = vv + 2;
        *(short8*)(Rp + prow + (size_t)s * 64 + 8 * (g ^ (s & 7))) = val;
    }
}

// ---------------------------------------------------------------------------
extern "C" void kernel_launch(void* const* d_in, const int* in_sizes, int n_in,
                              void* d_out, int out_size, void* d_ws, size_t ws_size,
                              hipStream_t stream) {
    const float* x = (const float*)d_in[0];   // [16,64,56,56] fp32
    const float* W = (const float*)d_in[1];   // [128,64,3,3]  fp32
    float* out = (float*)d_out;               // [16,128,56,56] fp32

    // ws layout (all bf16): Xp | Rp | Yp | Cp | Wf2 | Wt2  (~49 MB)
    const size_t XPN = (size_t)16 * 58 * 68 * 64;   // 4,038,656
    const size_t YPN = 2 * XPN;                      // 8,077,312
    short* Xp = (short*)d_ws;
    short* Rp = Xp + XPN;
    short* Yp = Rp + XPN;
    short* Cp = Yp + YPN;
    short* Wf2 = Cp + YPN;                // 73728 shorts
    short* Wt2 = Wf2 + 73728;             // 73728 shorts

    const int n4 = (int)((XPN + YPN) * 2 / 16);     // 1,514,496 (ZB_=5916)
    const int prep_blocks = ZB_ + 32 + 58 * 16;     // 6876
    hipLaunchKernelGGL(prep_kernel, dim3(prep_blocks), dim3(256), 0, stream,
                       x, W, (float4*)Rp, n4, Xp, Wf2, Wt2);

    dim3 b(256, 1, 1);
    // it0: c = shrink(MU * conv(x)); y = cp = c
    hipLaunchKernelGGL(conv_fwd, dim3(1792), b, 0, stream, Xp, Wf2, Yp, Cp,
                       (float*)nullptr, 0, 0.f);
    double t = 1.0;
    for (int it = 1; it <= 5; ++it) {
        hipLaunchKernelGGL(conv_t, dim3(896), b, 0, stream, Yp, Wt2, Xp, Rp);
        double tn = (1.0 + sqrt(1.0 + 4.0 * t * t)) / 2.0;
        float beta = (float)((t - 1.0) / tn);
        hipLaunchKernelGGL(conv_fwd, dim3(1792), b, 0, stream, Rp, Wf2, Yp, Cp,
                           (it == 5) ? out : (float*)nullptr, (it == 5) ? 2 : 1,
                           beta);
        t = tn;
    }
}